// Round 5
// baseline (132.386 us; speedup 1.0000x reference)
//
#include <hip/hip_runtime.h>
#include <math.h>

// Problem constants
constexpr int N = 8, C = 128, H = 64, W = 64;
constexpr int PIX = H * W;            // 4096
constexpr int KK = 49;                // 7x7 window

// ws layout in floats
constexpr size_t M_OFF   = 0;                        // M = W1^T W2, 128x128
constexpr size_t WT3_OFF = 16384;                    // W3 transposed [k][o]
constexpr size_t Z_OFF   = 65536;                    // z = M^T x, N*C*PIX
constexpr size_t YSZ     = (size_t)N * C * PIX;      // 4,194,304 floats
constexpr size_t SIM_OFF = Z_OFF + YSZ;              // sim: [n][hq][49][256]
constexpr size_t ATTSZ   = (size_t)N * 16 * KK * 256;// 1,605,632 floats
constexpr size_t U_OFF   = SIM_OFF + ATTSZ;          // u = PV(x), N*C*PIX

// ---------------------------------------------------------------------------
// K0: prep. Blocks 0..63: M[a][b] = sum_c W1[c][a]*W2[c][b]  (2 rows/block).
//     Blocks 64..67: Wt3[c][o] = W3[o][c].
// ---------------------------------------------------------------------------
__global__ __launch_bounds__(256) void prep(const float* __restrict__ w1,
                                            const float* __restrict__ w2,
                                            const float* __restrict__ w3,
                                            float* __restrict__ Mout,
                                            float* __restrict__ wt3) {
    int bid = blockIdx.x, tid = threadIdx.x;
    if (bid < 64) {
        int a = bid * 2 + (tid >> 7);
        int b = tid & 127;
        float s = 0.f;
        for (int c = 0; c < 128; c++)
            s = fmaf(w1[c * 128 + a], w2[c * 128 + b], s);
        Mout[a * 128 + b] = s;
    } else {
        int base = (bid - 64) * 4096;
        for (int i = tid; i < 4096; i += 256) {
            int idx = base + i;
            int o = idx & 127, c = idx >> 7;
            wt3[idx] = w3[o * 128 + c];     // wt3[c*128+o] = w3[o][c]
        }
    }
}

// ---------------------------------------------------------------------------
// K1: generic 1x1-conv GEMM. Block tile: 128 oc x 64 px, K=128 chunked by 32.
// ---------------------------------------------------------------------------
__global__ __launch_bounds__(256) void convk(const float* __restrict__ A,
                                             const float* __restrict__ Bsrc,
                                             float* __restrict__ Yout) {
    __shared__ float la[32 * 136];   // [k][oc], pad 8
    __shared__ float lb[32 * 72];    // [k][px], pad 8

    int bid = blockIdx.x;
    int pt  = bid & 63;
    int n   = bid >> 6;
    int p0  = pt * 64;

    const float* B = Bsrc + (size_t)n * C * PIX;
    float*       Y = Yout + (size_t)n * C * PIX;

    int tid = threadIdx.x;
    int tx  = tid & 15, ty = tid >> 4;
    int oc0 = ty * 8, px0 = tx * 4;

    float acc[8][4];
#pragma unroll
    for (int i = 0; i < 8; i++)
#pragma unroll
        for (int j = 0; j < 4; j++) acc[i][j] = 0.f;

    for (int kk = 0; kk < 128; kk += 32) {
#pragma unroll
        for (int i = 0; i < 4; i++) {
            int q   = tid + i * 256;
            int row = q >> 5;
            int c4  = (q & 31) * 4;
            *(float4*)&la[row * 136 + c4] =
                *(const float4*)&A[(kk + row) * 128 + c4];
        }
#pragma unroll
        for (int i = 0; i < 2; i++) {
            int q   = tid + i * 256;
            int row = q >> 4;
            int c4  = (q & 15) * 4;
            *(float4*)&lb[row * 72 + c4] =
                *(const float4*)&B[(size_t)(kk + row) * PIX + p0 + c4];
        }
        __syncthreads();

#pragma unroll 8
        for (int k = 0; k < 32; k++) {
            float4 a0 = *(float4*)&la[k * 136 + oc0];
            float4 a1 = *(float4*)&la[k * 136 + oc0 + 4];
            float4 b0 = *(float4*)&lb[k * 72 + px0];
            float a[8] = {a0.x, a0.y, a0.z, a0.w, a1.x, a1.y, a1.z, a1.w};
            float b[4] = {b0.x, b0.y, b0.z, b0.w};
#pragma unroll
            for (int i = 0; i < 8; i++)
#pragma unroll
                for (int j = 0; j < 4; j++)
                    acc[i][j] = fmaf(a[i], b[j], acc[i][j]);
        }
        __syncthreads();
    }

#pragma unroll
    for (int i = 0; i < 8; i++) {
        float4 v = make_float4(acc[i][0], acc[i][1], acc[i][2], acc[i][3]);
        *(float4*)&Y[(size_t)(oc0 + i) * PIX + p0 + px0] = v;
    }
}

// ---------------------------------------------------------------------------
// Window staging geometry (shared by simk / softpv):
// st[row 0..9][c 0..15][col 0..75]; image col v -> staged col 4+v.
// Halo cols 0..3 / 68..75 zeroed once; OOB rows staged as zero each chunk.
// Lane = (r = lane>>4, w4 = lane&15) owns 4 px: w = 4*w4 .. 4*w4+3 of row h0+r.
// Window read per (c, window-row): 3 ds_read_b128 at cols wpx, wpx+4, wpx+8
// giving rw[0..11]; tap (j, dj): rw[j + dj + 1]  (dj = 0..6 <-> dj' = dj-3).
// ---------------------------------------------------------------------------
constexpr int SR  = 10;   // staged rows: h0-3 .. h0+6
constexpr int SLW = 76;   // padded row width (floats)

// ---------------------------------------------------------------------------
// K2: sim[n][hq][k][px] = z(p) . x(p+dk)   (no softmax; no reduction needed)
// Grid 256 = n(8) x hq(16) x digrp(2). 256 thr = 4 waves; wave di = digrp*4+wid
// (di==7 idles). Each wave computes taps k = di*7 + dj for all 256 px, full C.
// ---------------------------------------------------------------------------
__global__ __launch_bounds__(256) void simk(const float* __restrict__ z,
                                            const float* __restrict__ x,
                                            float* __restrict__ sim) {
    __shared__ float st[SR * 16 * SLW];   // 12160 floats = 48.6 KB

    int bid   = blockIdx.x;
    int digrp = bid & 1;
    int hq    = (bid >> 1) & 15;
    int n     = bid >> 5;
    int h0    = hq * 4;

    int tid  = threadIdx.x;
    int wid  = tid >> 6;
    int lane = tid & 63;
    int r    = lane >> 4;
    int w4   = lane & 15;
    int wpx  = w4 * 4;
    int di   = digrp * 4 + wid;          // 0..7; 7 = idle

    const float* zb = z + (size_t)n * C * PIX;
    const float* xb = x + (size_t)n * C * PIX;
    float* simb = sim + ((size_t)(n * 16 + hq) * KK) * 256;

    // zero halo columns once
    for (int idx = tid; idx < SR * 16 * 8; idx += 256) {
        int col8 = idx & 7;
        int c    = (idx >> 3) & 15;
        int row  = idx >> 7;
        int col  = (col8 < 4) ? col8 : 64 + col8;
        st[(row * 16 + c) * SLW + col] = 0.f;
    }
    __syncthreads();

    float acc[7][4];
#pragma unroll
    for (int dj = 0; dj < 7; dj++)
#pragma unroll
        for (int j = 0; j < 4; j++) acc[dj][j] = 0.f;

    for (int ch = 0; ch < C; ch += 16) {
        // stage 10 rows x 16 c x 64 w (interior only)
#pragma unroll
        for (int i = 0; i < 10; i++) {
            int q  = tid + i * 256;
            int qw = q & 15, qc = (q >> 4) & 15, qr = q >> 8;
            int hh = h0 - 3 + qr;
            float4 v = make_float4(0.f, 0.f, 0.f, 0.f);
            if ((unsigned)hh < 64u)
                v = *(const float4*)&xb[(size_t)(ch + qc) * PIX + hh * 64 + qw * 4];
            *(float4*)&st[(qr * 16 + qc) * SLW + 4 + qw * 4] = v;
        }
        __syncthreads();

        if (di < 7) {
#pragma unroll
            for (int c = 0; c < 16; c++) {
                float4 z4 = *(const float4*)&zb[(size_t)(ch + c) * PIX + (h0 + r) * 64 + wpx];
                const float* rp = &st[((r + di) * 16 + c) * SLW + wpx];
                float rw[12];
                *(float4*)&rw[0] = *(const float4*)&rp[0];
                *(float4*)&rw[4] = *(const float4*)&rp[4];
                *(float4*)&rw[8] = *(const float4*)&rp[8];
                const float* zp = (const float*)&z4;
#pragma unroll
                for (int dj = 0; dj < 7; dj++)
#pragma unroll
                    for (int j = 0; j < 4; j++)
                        acc[dj][j] = fmaf(zp[j], rw[j + dj + 1], acc[dj][j]);
            }
        }
        __syncthreads();
    }

    if (di < 7) {
#pragma unroll
        for (int dj = 0; dj < 7; dj++) {
            int k = di * 7 + dj;
            float4 v = make_float4(acc[dj][0], acc[dj][1], acc[dj][2], acc[dj][3]);
            *(float4*)&simb[(size_t)k * 256 + r * 64 + wpx] = v;
        }
    }
}

// ---------------------------------------------------------------------------
// K3: softmax(sim) -> attn (LDS) -> u[c](p) = sum_k attn_k(p) x_c(p+dk)
// Grid 256 = n(8) x hq(16) x chalf(2). 256 thr = 4 waves; wave owns 4 channels
// per 16-channel chunk (4 chunks over the 64-channel half).
// ---------------------------------------------------------------------------
__global__ __launch_bounds__(256) void softpv(const float* __restrict__ sim,
                                              const float* __restrict__ x,
                                              float* __restrict__ u) {
    __shared__ float st[SR * 16 * SLW];   // 48.6 KB
    __shared__ float al[KK * 256];        // 50.2 KB attn

    int bid   = blockIdx.x;
    int chalf = bid & 1;
    int hq    = (bid >> 1) & 15;
    int n     = bid >> 5;
    int h0    = hq * 4;

    int tid  = threadIdx.x;
    int wid  = tid >> 6;
    int lane = tid & 63;
    int r    = lane >> 4;
    int w4   = lane & 15;
    int wpx  = w4 * 4;

    const float* xb   = x + (size_t)n * C * PIX;
    const float* simb = sim + ((size_t)(n * 16 + hq) * KK) * 256;
    float* ub = u + (size_t)n * C * PIX;

    // softmax: one px per thread (redundant across the 2 chalf blocks; cheap)
    {
        int px = tid;
        float sv[KK];
        float m = -1e30f;
#pragma unroll
        for (int k = 0; k < KK; k++) {
            sv[k] = simb[(size_t)k * 256 + px];
            m = fmaxf(m, sv[k]);
        }
        float s = 0.f;
#pragma unroll
        for (int k = 0; k < KK; k++) {
            float e = __expf(sv[k] - m);
            sv[k] = e;
            s += e;
        }
        float inv = 1.f / s;
#pragma unroll
        for (int k = 0; k < KK; k++) al[k * 256 + px] = sv[k] * inv;
    }

    // zero halo columns once
    for (int idx = tid; idx < SR * 16 * 8; idx += 256) {
        int col8 = idx & 7;
        int c    = (idx >> 3) & 15;
        int row  = idx >> 7;
        int col  = (col8 < 4) ? col8 : 64 + col8;
        st[(row * 16 + c) * SLW + col] = 0.f;
    }
    __syncthreads();

    for (int ch = 0; ch < 4; ch++) {            // 4 chunks of 16 channels
        int c0 = chalf * 64 + ch * 16;
#pragma unroll
        for (int i = 0; i < 10; i++) {
            int q  = tid + i * 256;
            int qw = q & 15, qc = (q >> 4) & 15, qr = q >> 8;
            int hh = h0 - 3 + qr;
            float4 v = make_float4(0.f, 0.f, 0.f, 0.f);
            if ((unsigned)hh < 64u)
                v = *(const float4*)&xb[(size_t)(c0 + qc) * PIX + hh * 64 + qw * 4];
            *(float4*)&st[(qr * 16 + qc) * SLW + 4 + qw * 4] = v;
        }
        __syncthreads();

        float u4[4][4];
#pragma unroll
        for (int cl = 0; cl < 4; cl++)
#pragma unroll
            for (int j = 0; j < 4; j++) u4[cl][j] = 0.f;

        int cw = wid * 4;   // wave's channel group within chunk
#pragma unroll
        for (int di = 0; di < 7; di++) {
            float4 a4[7];
#pragma unroll
            for (int dj = 0; dj < 7; dj++)
                a4[dj] = *(const float4*)&al[(di * 7 + dj) * 256 + r * 64 + wpx];
#pragma unroll
            for (int cl = 0; cl < 4; cl++) {
                const float* rp = &st[((r + di) * 16 + cw + cl) * SLW + wpx];
                float rw[12];
                *(float4*)&rw[0] = *(const float4*)&rp[0];
                *(float4*)&rw[4] = *(const float4*)&rp[4];
                *(float4*)&rw[8] = *(const float4*)&rp[8];
#pragma unroll
                for (int dj = 0; dj < 7; dj++) {
                    const float* ap = (const float*)&a4[dj];
#pragma unroll
                    for (int j = 0; j < 4; j++)
                        u4[cl][j] = fmaf(ap[j], rw[j + dj + 1], u4[cl][j]);
                }
            }
        }

#pragma unroll
        for (int cl = 0; cl < 4; cl++) {
            int c = c0 + cw + cl;
            float4 v = make_float4(u4[cl][0], u4[cl][1], u4[cl][2], u4[cl][3]);
            *(float4*)&ub[(size_t)c * PIX + (h0 + r) * 64 + wpx] = v;
        }
        __syncthreads();
    }
}

// ---------------------------------------------------------------------------
extern "C" void kernel_launch(void* const* d_in, const int* in_sizes, int n_in,
                              void* d_out, int out_size, void* d_ws, size_t ws_size,
                              hipStream_t stream) {
    const float* x  = (const float*)d_in[0];
    const float* w1 = (const float*)d_in[1];
    const float* w2 = (const float*)d_in[2];
    const float* w3 = (const float*)d_in[3];
    float* wsf = (float*)d_ws;

    prep<<<68, 256, 0, stream>>>(w1, w2, w3, wsf + M_OFF, wsf + WT3_OFF);
    convk<<<512, 256, 0, stream>>>(wsf + M_OFF, x, wsf + Z_OFF);              // z = M^T x
    simk<<<256, 256, 0, stream>>>(wsf + Z_OFF, x, wsf + SIM_OFF);             // sim
    softpv<<<256, 256, 0, stream>>>(wsf + SIM_OFF, x, wsf + U_OFF);           // attn, u
    convk<<<512, 256, 0, stream>>>(wsf + WT3_OFF, wsf + U_OFF, (float*)d_out); // out = W3 u
}

// Round 6
// 117.056 us; speedup vs baseline: 1.1310x; 1.1310x over previous
//
#include <hip/hip_runtime.h>
#include <math.h>

// Problem constants
constexpr int N = 8, C = 128, H = 64, W = 64;
constexpr int PIX = H * W;            // 4096
constexpr int KK = 49;                // 7x7 window

// ws layout in floats
constexpr size_t M_OFF   = 0;                        // M = W1^T W2, 128x128
constexpr size_t WT3_OFF = 16384;                    // W3 transposed [k][o]
constexpr size_t Z_OFF   = 65536;                    // z = M^T x, N*C*PIX
constexpr size_t YSZ     = (size_t)N * C * PIX;      // 4,194,304 floats
constexpr size_t SIM_OFF = Z_OFF + YSZ;              // sim: [n][hq][49][256]
constexpr size_t ATTSZ   = (size_t)N * 16 * KK * 256;// 1,605,632 floats
constexpr size_t U_OFF   = SIM_OFF + ATTSZ;          // u = PV(x), N*C*PIX

constexpr int SLW = 76;   // padded stage row width; image col v -> col 4+v

// ---------------------------------------------------------------------------
// K0: prep. Blocks 0..63: M[a][b] = sum_c W1[c][a]*W2[c][b]  (2 rows/block).
//     Blocks 64..67: Wt3[c][o] = W3[o][c].
// ---------------------------------------------------------------------------
__global__ __launch_bounds__(256) void prep(const float* __restrict__ w1,
                                            const float* __restrict__ w2,
                                            const float* __restrict__ w3,
                                            float* __restrict__ Mout,
                                            float* __restrict__ wt3) {
    int bid = blockIdx.x, tid = threadIdx.x;
    if (bid < 64) {
        int a = bid * 2 + (tid >> 7);
        int b = tid & 127;
        float s = 0.f;
        for (int c = 0; c < 128; c++)
            s = fmaf(w1[c * 128 + a], w2[c * 128 + b], s);
        Mout[a * 128 + b] = s;
    } else {
        int base = (bid - 64) * 4096;
        for (int i = tid; i < 4096; i += 256) {
            int idx = base + i;
            int o = idx & 127, c = idx >> 7;
            wt3[idx] = w3[o * 128 + c];     // wt3[c*128+o] = w3[o][c]
        }
    }
}

// ---------------------------------------------------------------------------
// K1: generic 1x1-conv GEMM. Block tile: 128 oc x 64 px, K=128 chunked by 32.
// ---------------------------------------------------------------------------
__global__ __launch_bounds__(256) void convk(const float* __restrict__ A,
                                             const float* __restrict__ Bsrc,
                                             float* __restrict__ Yout) {
    __shared__ float la[32 * 136];   // [k][oc], pad 8
    __shared__ float lb[32 * 72];    // [k][px], pad 8

    int bid = blockIdx.x;
    int pt  = bid & 63;
    int n   = bid >> 6;
    int p0  = pt * 64;

    const float* B = Bsrc + (size_t)n * C * PIX;
    float*       Y = Yout + (size_t)n * C * PIX;

    int tid = threadIdx.x;
    int tx  = tid & 15, ty = tid >> 4;
    int oc0 = ty * 8, px0 = tx * 4;

    float acc[8][4];
#pragma unroll
    for (int i = 0; i < 8; i++)
#pragma unroll
        for (int j = 0; j < 4; j++) acc[i][j] = 0.f;

    for (int kk = 0; kk < 128; kk += 32) {
#pragma unroll
        for (int i = 0; i < 4; i++) {
            int q   = tid + i * 256;
            int row = q >> 5;
            int c4  = (q & 31) * 4;
            *(float4*)&la[row * 136 + c4] =
                *(const float4*)&A[(kk + row) * 128 + c4];
        }
#pragma unroll
        for (int i = 0; i < 2; i++) {
            int q   = tid + i * 256;
            int row = q >> 4;
            int c4  = (q & 15) * 4;
            *(float4*)&lb[row * 72 + c4] =
                *(const float4*)&B[(size_t)(kk + row) * PIX + p0 + c4];
        }
        __syncthreads();

#pragma unroll 8
        for (int k = 0; k < 32; k++) {
            float4 a0 = *(float4*)&la[k * 136 + oc0];
            float4 a1 = *(float4*)&la[k * 136 + oc0 + 4];
            float4 b0 = *(float4*)&lb[k * 72 + px0];
            float a[8] = {a0.x, a0.y, a0.z, a0.w, a1.x, a1.y, a1.z, a1.w};
            float b[4] = {b0.x, b0.y, b0.z, b0.w};
#pragma unroll
            for (int i = 0; i < 8; i++)
#pragma unroll
                for (int j = 0; j < 4; j++)
                    acc[i][j] = fmaf(a[i], b[j], acc[i][j]);
        }
        __syncthreads();
    }

#pragma unroll
    for (int i = 0; i < 8; i++) {
        float4 v = make_float4(acc[i][0], acc[i][1], acc[i][2], acc[i][3]);
        *(float4*)&Y[(size_t)(oc0 + i) * PIX + p0 + px0] = v;
    }
}

// ---------------------------------------------------------------------------
// K2: sim[n][hq][k][px] for k = di*7+dj.  ONE di PER BLOCK (4 staged rows).
// Grid 896: bid = di*128 + g, g = n*16+hq  (di-blocks of same g share an XCD
// under bid%8 round-robin, so z/x slices are L2-local).
// Block 256 thr = 4 waves; wave wid = c-quarter (4 channels per 16-chunk).
// Lane: r = lane>>4 (query row), w4 = lane&15 -> 4 px.  Per (c):
// 1 global z b128 + 3 ds b128 -> 28 FMA into acc[7][4]. LDS reduce over waves.
// ---------------------------------------------------------------------------
__global__ __launch_bounds__(256) void simk2(const float* __restrict__ z,
                                             const float* __restrict__ x,
                                             float* __restrict__ sim) {
    __shared__ __align__(16) float st[5376];  // stage 4*16*76=4864 | red 3*7*256=5376

    int bid = blockIdx.x;
    int di  = bid >> 7;          // 0..6
    int g   = bid & 127;
    int n   = g >> 4;
    int hq  = g & 15;
    int h0  = hq * 4;

    int tid  = threadIdx.x;
    int wid  = tid >> 6;
    int lane = tid & 63;
    int r = lane >> 4, w4 = lane & 15, wpx = w4 * 4;

    const float* zb = z + (size_t)n * C * PIX;
    const float* xb = x + (size_t)n * C * PIX;
    float* simb = sim + ((size_t)(n * 16 + hq) * KK) * 256;

    // zero halo columns (4 rows x 16 c x 8 halo cols)
    for (int idx = tid; idx < 4 * 16 * 8; idx += 256) {
        int col8 = idx & 7;
        int c    = (idx >> 3) & 15;
        int row  = idx >> 7;
        int col  = (col8 < 4) ? col8 : 64 + col8;
        st[(row * 16 + c) * SLW + col] = 0.f;
    }
    __syncthreads();

    float acc[7][4];
#pragma unroll
    for (int dj = 0; dj < 7; dj++)
#pragma unroll
        for (int j = 0; j < 4; j++) acc[dj][j] = 0.f;

    for (int ch = 0; ch < C; ch += 16) {
        // stage window rows h0+di-3+qr, qr=0..3, 16 channels
#pragma unroll
        for (int i = 0; i < 4; i++) {
            int q  = tid + i * 256;
            int qw = q & 15, qc = (q >> 4) & 15, qr = q >> 8;
            int hh = h0 + di - 3 + qr;
            float4 v = make_float4(0.f, 0.f, 0.f, 0.f);
            if ((unsigned)hh < 64u)
                v = *(const float4*)&xb[(size_t)(ch + qc) * PIX + hh * 64 + qw * 4];
            *(float4*)&st[(qr * 16 + qc) * SLW + 4 + qw * 4] = v;
        }
        __syncthreads();

#pragma unroll
        for (int c = 0; c < 4; c++) {
            int cl = wid * 4 + c;
            float4 z4 = *(const float4*)&zb[(size_t)(ch + cl) * PIX + (h0 + r) * 64 + wpx];
            const float* rp = &st[(r * 16 + cl) * SLW + wpx];
            float rw[12];
            *(float4*)&rw[0] = *(const float4*)&rp[0];
            *(float4*)&rw[4] = *(const float4*)&rp[4];
            *(float4*)&rw[8] = *(const float4*)&rp[8];
            const float* zp = (const float*)&z4;
#pragma unroll
            for (int dj = 0; dj < 7; dj++)
#pragma unroll
                for (int j = 0; j < 4; j++)
                    acc[dj][j] = fmaf(zp[j], rw[j + dj + 1], acc[dj][j]);
        }
        __syncthreads();
    }

    // cross-wave channel reduction (stage buffer dead)
    if (wid > 0) {
#pragma unroll
        for (int dj = 0; dj < 7; dj++) {
            float4 v = make_float4(acc[dj][0], acc[dj][1], acc[dj][2], acc[dj][3]);
            *(float4*)&st[((wid - 1) * 7 + dj) * 256 + lane * 4] = v;
        }
    }
    __syncthreads();
    if (wid == 0) {
#pragma unroll
        for (int s = 0; s < 3; s++)
#pragma unroll
            for (int dj = 0; dj < 7; dj++) {
                float4 v = *(const float4*)&st[(s * 7 + dj) * 256 + lane * 4];
                acc[dj][0] += v.x; acc[dj][1] += v.y;
                acc[dj][2] += v.z; acc[dj][3] += v.w;
            }
#pragma unroll
        for (int dj = 0; dj < 7; dj++) {
            int k = di * 7 + dj;
            float4 v = make_float4(acc[dj][0], acc[dj][1], acc[dj][2], acc[dj][3]);
            *(float4*)&simb[(size_t)k * 256 + r * 64 + wpx] = v;
        }
    }
}

// ---------------------------------------------------------------------------
// K3: softmax(sim) -> attn (bf16 in LDS) -> u[c](p) = sum_k attn_k(p) x_c(p+dk)
// Grid 512: bid = cqb*128 + g (c-quarter per block, XCD co-located by g).
// Block 512 thr = 8 waves; wave handles 2 channels of each 16-c chunk.
// ---------------------------------------------------------------------------
__global__ __launch_bounds__(512) void softpv2(const float* __restrict__ sim,
                                               const float* __restrict__ x,
                                               float* __restrict__ u) {
    __shared__ __align__(16) float st[10 * 16 * SLW];      // 48.6 KB
    __shared__ __align__(16) unsigned short al[KK * 256];  // 25.1 KB bf16 attn

    int bid = blockIdx.x;
    int cqb = bid >> 7;          // 0..3 c-quarter
    int g   = bid & 127;
    int n   = g >> 4;
    int hq  = g & 15;
    int h0  = hq * 4;

    int tid  = threadIdx.x;
    int wid  = tid >> 6;
    int lane = tid & 63;
    int r = lane >> 4, w4 = lane & 15, wpx = w4 * 4;

    const float* xb   = x + (size_t)n * C * PIX;
    const float* simb = sim + ((size_t)(n * 16 + hq) * KK) * 256;
    float* ub = u + (size_t)n * C * PIX;

    // Phase 1: softmax, one px per thread (256 active), attn -> bf16 LDS
    if (tid < 256) {
        int px = tid;
        float sv[KK];
        float m = -1e30f;
#pragma unroll
        for (int k = 0; k < KK; k++) {
            sv[k] = simb[(size_t)k * 256 + px];
            m = fmaxf(m, sv[k]);
        }
        float s = 0.f;
#pragma unroll
        for (int k = 0; k < KK; k++) {
            float e = __expf(sv[k] - m);
            sv[k] = e; s += e;
        }
        float inv = 1.f / s;
#pragma unroll
        for (int k = 0; k < KK; k++) {
            unsigned ui = __float_as_uint(sv[k] * inv);
            ui += 0x7FFFu + ((ui >> 16) & 1u);   // RNE to bf16
            al[k * 256 + px] = (unsigned short)(ui >> 16);
        }
    }
    // zero halo columns (10 rows x 16 c x 8 cols)
    for (int idx = tid; idx < 10 * 16 * 8; idx += 512) {
        int col8 = idx & 7;
        int c    = (idx >> 3) & 15;
        int row  = idx >> 7;
        int col  = (col8 < 4) ? col8 : 64 + col8;
        st[(row * 16 + c) * SLW + col] = 0.f;
    }
    __syncthreads();

    for (int ch2 = 0; ch2 < 2; ch2++) {
        int c0 = cqb * 32 + ch2 * 16;
        // stage 10 rows x 16 c
#pragma unroll
        for (int i = 0; i < 5; i++) {
            int q  = tid + i * 512;
            int qw = q & 15, qc = (q >> 4) & 15, qr = q >> 8;
            int hh = h0 - 3 + qr;
            float4 v = make_float4(0.f, 0.f, 0.f, 0.f);
            if ((unsigned)hh < 64u)
                v = *(const float4*)&xb[(size_t)(c0 + qc) * PIX + hh * 64 + qw * 4];
            *(float4*)&st[(qr * 16 + qc) * SLW + 4 + qw * 4] = v;
        }
        __syncthreads();

        int cw = wid * 2;
        float u4[2][4];
#pragma unroll
        for (int cl = 0; cl < 2; cl++)
#pragma unroll
            for (int j = 0; j < 4; j++) u4[cl][j] = 0.f;

        for (int di = 0; di < 7; di++) {
            float a[7][4];
#pragma unroll
            for (int dj = 0; dj < 7; dj++) {
                uint2 p = *(const uint2*)&al[(di * 7 + dj) * 256 + r * 64 + wpx];
                a[dj][0] = __uint_as_float((p.x & 0xFFFFu) << 16);
                a[dj][1] = __uint_as_float(p.x & 0xFFFF0000u);
                a[dj][2] = __uint_as_float((p.y & 0xFFFFu) << 16);
                a[dj][3] = __uint_as_float(p.y & 0xFFFF0000u);
            }
#pragma unroll
            for (int cl = 0; cl < 2; cl++) {
                const float* rp = &st[((r + di) * 16 + cw + cl) * SLW + wpx];
                float rw[12];
                *(float4*)&rw[0] = *(const float4*)&rp[0];
                *(float4*)&rw[4] = *(const float4*)&rp[4];
                *(float4*)&rw[8] = *(const float4*)&rp[8];
#pragma unroll
                for (int dj = 0; dj < 7; dj++)
#pragma unroll
                    for (int j = 0; j < 4; j++)
                        u4[cl][j] = fmaf(a[dj][j], rw[j + dj + 1], u4[cl][j]);
            }
        }

#pragma unroll
        for (int cl = 0; cl < 2; cl++) {
            int c = c0 + cw + cl;
            float4 v = make_float4(u4[cl][0], u4[cl][1], u4[cl][2], u4[cl][3]);
            *(float4*)&ub[(size_t)c * PIX + (h0 + r) * 64 + wpx] = v;
        }
        __syncthreads();
    }
}

// ---------------------------------------------------------------------------
extern "C" void kernel_launch(void* const* d_in, const int* in_sizes, int n_in,
                              void* d_out, int out_size, void* d_ws, size_t ws_size,
                              hipStream_t stream) {
    const float* x  = (const float*)d_in[0];
    const float* w1 = (const float*)d_in[1];
    const float* w2 = (const float*)d_in[2];
    const float* w3 = (const float*)d_in[3];
    float* wsf = (float*)d_ws;

    prep<<<68, 256, 0, stream>>>(w1, w2, w3, wsf + M_OFF, wsf + WT3_OFF);
    convk<<<512, 256, 0, stream>>>(wsf + M_OFF, x, wsf + Z_OFF);               // z = M^T x
    simk2<<<896, 256, 0, stream>>>(wsf + Z_OFF, x, wsf + SIM_OFF);             // sim
    softpv2<<<512, 512, 0, stream>>>(wsf + SIM_OFF, x, wsf + U_OFF);           // attn, u
    convk<<<512, 256, 0, stream>>>(wsf + WT3_OFF, wsf + U_OFF, (float*)d_out); // out = W3 u
}

// Round 7
// 110.585 us; speedup vs baseline: 1.1971x; 1.0585x over previous
//
#include <hip/hip_runtime.h>
#include <math.h>

// Problem constants
constexpr int N = 8, C = 128, H = 64, W = 64;
constexpr int PIX = H * W;            // 4096
constexpr int KK = 49;                // 7x7 window

// ws layout in floats
constexpr size_t M_OFF   = 0;                        // M = W1^T W2, 128x128
constexpr size_t WT3_OFF = 16384;                    // W3 transposed [k][o]
constexpr size_t Z_OFF   = 65536;                    // z = M^T x, N*C*PIX
constexpr size_t YSZ     = (size_t)N * C * PIX;      // 4,194,304 floats
constexpr size_t SIM_OFF = Z_OFF + YSZ;              // sim: [n][hq][49][256]
constexpr size_t ATTSZ   = (size_t)N * 16 * KK * 256;// 1,605,632 floats
constexpr size_t U_OFF   = SIM_OFF + ATTSZ;          // u = PV(x), N*C*PIX

constexpr int SLW = 76;   // padded stage row width; image col v -> col 4+v

// ---------------------------------------------------------------------------
// K0: prep. Blocks 0..63: M[a][b] = sum_c W1[c][a]*W2[c][b]  (2 rows/block).
//     Blocks 64..67: Wt3[c][o] = W3[o][c].
// ---------------------------------------------------------------------------
__global__ __launch_bounds__(256) void prep(const float* __restrict__ w1,
                                            const float* __restrict__ w2,
                                            const float* __restrict__ w3,
                                            float* __restrict__ Mout,
                                            float* __restrict__ wt3) {
    int bid = blockIdx.x, tid = threadIdx.x;
    if (bid < 64) {
        int a = bid * 2 + (tid >> 7);
        int b = tid & 127;
        float s = 0.f;
        for (int c = 0; c < 128; c++)
            s = fmaf(w1[c * 128 + a], w2[c * 128 + b], s);
        Mout[a * 128 + b] = s;
    } else {
        int base = (bid - 64) * 4096;
        for (int i = tid; i < 4096; i += 256) {
            int idx = base + i;
            int o = idx & 127, c = idx >> 7;
            wt3[idx] = w3[o * 128 + c];     // wt3[c*128+o] = w3[o][c]
        }
    }
}

// ---------------------------------------------------------------------------
// K1: generic 1x1-conv GEMM. Block tile: 128 oc x 64 px, K=128 chunked by 32.
// ---------------------------------------------------------------------------
__global__ __launch_bounds__(256) void convk(const float* __restrict__ A,
                                             const float* __restrict__ Bsrc,
                                             float* __restrict__ Yout) {
    __shared__ float la[32 * 136];   // [k][oc], pad 8
    __shared__ float lb[32 * 72];    // [k][px], pad 8

    int bid = blockIdx.x;
    int pt  = bid & 63;
    int n   = bid >> 6;
    int p0  = pt * 64;

    const float* B = Bsrc + (size_t)n * C * PIX;
    float*       Y = Yout + (size_t)n * C * PIX;

    int tid = threadIdx.x;
    int tx  = tid & 15, ty = tid >> 4;
    int oc0 = ty * 8, px0 = tx * 4;

    float acc[8][4];
#pragma unroll
    for (int i = 0; i < 8; i++)
#pragma unroll
        for (int j = 0; j < 4; j++) acc[i][j] = 0.f;

    for (int kk = 0; kk < 128; kk += 32) {
#pragma unroll
        for (int i = 0; i < 4; i++) {
            int q   = tid + i * 256;
            int row = q >> 5;
            int c4  = (q & 31) * 4;
            *(float4*)&la[row * 136 + c4] =
                *(const float4*)&A[(kk + row) * 128 + c4];
        }
#pragma unroll
        for (int i = 0; i < 2; i++) {
            int q   = tid + i * 256;
            int row = q >> 4;
            int c4  = (q & 15) * 4;
            *(float4*)&lb[row * 72 + c4] =
                *(const float4*)&B[(size_t)(kk + row) * PIX + p0 + c4];
        }
        __syncthreads();

#pragma unroll 8
        for (int k = 0; k < 32; k++) {
            float4 a0 = *(float4*)&la[k * 136 + oc0];
            float4 a1 = *(float4*)&la[k * 136 + oc0 + 4];
            float4 b0 = *(float4*)&lb[k * 72 + px0];
            float a[8] = {a0.x, a0.y, a0.z, a0.w, a1.x, a1.y, a1.z, a1.w};
            float b[4] = {b0.x, b0.y, b0.z, b0.w};
#pragma unroll
            for (int i = 0; i < 8; i++)
#pragma unroll
                for (int j = 0; j < 4; j++)
                    acc[i][j] = fmaf(a[i], b[j], acc[i][j]);
        }
        __syncthreads();
    }

#pragma unroll
    for (int i = 0; i < 8; i++) {
        float4 v = make_float4(acc[i][0], acc[i][1], acc[i][2], acc[i][3]);
        *(float4*)&Y[(size_t)(oc0 + i) * PIX + p0 + px0] = v;
    }
}

// ---------------------------------------------------------------------------
// K2: sim[n][hq][k][px] for k = di*7+dj.  ONE di PER BLOCK (4 staged rows).
// Grid 896: bid = di*128 + g, g = n*16+hq.
// LDS stage layout: st[(c*4 + row)*SLW + col]  -- c-major so the 4 query-row
// lanes (r-stride = 1 row = 76 floats = 12 banks) never collide.
// ---------------------------------------------------------------------------
__global__ __launch_bounds__(256) void simk2(const float* __restrict__ z,
                                             const float* __restrict__ x,
                                             float* __restrict__ sim) {
    __shared__ __align__(16) float st[5376];  // stage 16*4*76=4864 | red 3*7*256=5376

    int bid = blockIdx.x;
    int di  = bid >> 7;          // 0..6
    int g   = bid & 127;
    int n   = g >> 4;
    int hq  = g & 15;
    int h0  = hq * 4;

    int tid  = threadIdx.x;
    int wid  = tid >> 6;
    int lane = tid & 63;
    int r = lane >> 4, w4 = lane & 15, wpx = w4 * 4;

    const float* zb = z + (size_t)n * C * PIX;
    const float* xb = x + (size_t)n * C * PIX;
    float* simb = sim + ((size_t)(n * 16 + hq) * KK) * 256;

    // zero halo columns (16 c x 4 rows x 8 halo cols)
    for (int idx = tid; idx < 16 * 4 * 8; idx += 256) {
        int col8 = idx & 7;
        int row  = (idx >> 3) & 3;
        int c    = idx >> 5;
        int col  = (col8 < 4) ? col8 : 64 + col8;
        st[(c * 4 + row) * SLW + col] = 0.f;
    }
    __syncthreads();

    float acc[7][4];
#pragma unroll
    for (int dj = 0; dj < 7; dj++)
#pragma unroll
        for (int j = 0; j < 4; j++) acc[dj][j] = 0.f;

    for (int ch = 0; ch < C; ch += 16) {
        // stage window rows h0+di-3+qr, qr=0..3, 16 channels (c-major layout)
#pragma unroll
        for (int i = 0; i < 4; i++) {
            int q  = tid + i * 256;
            int qw = q & 15, qc = (q >> 4) & 15, qr = q >> 8;
            int hh = h0 + di - 3 + qr;
            float4 v = make_float4(0.f, 0.f, 0.f, 0.f);
            if ((unsigned)hh < 64u)
                v = *(const float4*)&xb[(size_t)(ch + qc) * PIX + hh * 64 + qw * 4];
            *(float4*)&st[(qc * 4 + qr) * SLW + 4 + qw * 4] = v;
        }
        __syncthreads();

#pragma unroll
        for (int c = 0; c < 4; c++) {
            int cl = wid * 4 + c;
            float4 z4 = *(const float4*)&zb[(size_t)(ch + cl) * PIX + (h0 + r) * 64 + wpx];
            const float* rp = &st[(cl * 4 + r) * SLW + wpx];
            float rw[12];
            *(float4*)&rw[0] = *(const float4*)&rp[0];
            *(float4*)&rw[4] = *(const float4*)&rp[4];
            *(float4*)&rw[8] = *(const float4*)&rp[8];
            const float* zp = (const float*)&z4;
#pragma unroll
            for (int dj = 0; dj < 7; dj++)
#pragma unroll
                for (int j = 0; j < 4; j++)
                    acc[dj][j] = fmaf(zp[j], rw[j + dj + 1], acc[dj][j]);
        }
        __syncthreads();
    }

    // cross-wave channel reduction (stage buffer dead)
    if (wid > 0) {
#pragma unroll
        for (int dj = 0; dj < 7; dj++) {
            float4 v = make_float4(acc[dj][0], acc[dj][1], acc[dj][2], acc[dj][3]);
            *(float4*)&st[((wid - 1) * 7 + dj) * 256 + lane * 4] = v;
        }
    }
    __syncthreads();
    if (wid == 0) {
#pragma unroll
        for (int s = 0; s < 3; s++)
#pragma unroll
            for (int dj = 0; dj < 7; dj++) {
                float4 v = *(const float4*)&st[(s * 7 + dj) * 256 + lane * 4];
                acc[dj][0] += v.x; acc[dj][1] += v.y;
                acc[dj][2] += v.z; acc[dj][3] += v.w;
            }
#pragma unroll
        for (int dj = 0; dj < 7; dj++) {
            int k = di * 7 + dj;
            float4 v = make_float4(acc[dj][0], acc[dj][1], acc[dj][2], acc[dj][3]);
            *(float4*)&simb[(size_t)k * 256 + r * 64 + wpx] = v;
        }
    }
}

// ---------------------------------------------------------------------------
// K3: softmax(sim) -> attn (bf16 in LDS) -> u[c](p) = sum_k attn_k(p) x_c(p+dk)
// Grid 512: bid = cqb*128 + g.  Stage layout: st[(c*10 + row)*SLW + col]
// (c-major; r-stride = 76 floats = 12 banks -> conflict-free b128 reads).
// ---------------------------------------------------------------------------
__global__ __launch_bounds__(512) void softpv2(const float* __restrict__ sim,
                                               const float* __restrict__ x,
                                               float* __restrict__ u) {
    __shared__ __align__(16) float st[16 * 10 * SLW];      // 48.6 KB
    __shared__ __align__(16) unsigned short al[KK * 256];  // 25.1 KB bf16 attn

    int bid = blockIdx.x;
    int cqb = bid >> 7;          // 0..3 c-quarter
    int g   = bid & 127;
    int n   = g >> 4;
    int hq  = g & 15;
    int h0  = hq * 4;

    int tid  = threadIdx.x;
    int wid  = tid >> 6;
    int lane = tid & 63;
    int r = lane >> 4, w4 = lane & 15, wpx = w4 * 4;

    const float* xb   = x + (size_t)n * C * PIX;
    const float* simb = sim + ((size_t)(n * 16 + hq) * KK) * 256;
    float* ub = u + (size_t)n * C * PIX;

    // Phase 1: softmax, one px per thread (256 active), attn -> bf16 LDS
    if (tid < 256) {
        int px = tid;
        float sv[KK];
        float m = -1e30f;
#pragma unroll
        for (int k = 0; k < KK; k++) {
            sv[k] = simb[(size_t)k * 256 + px];
            m = fmaxf(m, sv[k]);
        }
        float s = 0.f;
#pragma unroll
        for (int k = 0; k < KK; k++) {
            float e = __expf(sv[k] - m);
            sv[k] = e; s += e;
        }
        float inv = 1.f / s;
#pragma unroll
        for (int k = 0; k < KK; k++) {
            unsigned ui = __float_as_uint(sv[k] * inv);
            ui += 0x7FFFu + ((ui >> 16) & 1u);   // RNE to bf16
            al[k * 256 + px] = (unsigned short)(ui >> 16);
        }
    }
    // zero halo columns (16 c x 10 rows x 8 cols)
    for (int idx = tid; idx < 16 * 10 * 8; idx += 512) {
        int col8 = idx & 7;
        int row  = (idx >> 3) % 10;
        int c    = (idx >> 3) / 10;
        int col  = (col8 < 4) ? col8 : 64 + col8;
        st[(c * 10 + row) * SLW + col] = 0.f;
    }
    __syncthreads();

    for (int ch2 = 0; ch2 < 2; ch2++) {
        int c0 = cqb * 32 + ch2 * 16;
        // stage 16 c x 10 rows (c-major layout)
#pragma unroll
        for (int i = 0; i < 5; i++) {
            int q  = tid + i * 512;
            int qw = q & 15, qc = (q >> 4) & 15, qr = q >> 8;
            int hh = h0 - 3 + qr;
            float4 v = make_float4(0.f, 0.f, 0.f, 0.f);
            if ((unsigned)hh < 64u)
                v = *(const float4*)&xb[(size_t)(c0 + qc) * PIX + hh * 64 + qw * 4];
            *(float4*)&st[(qc * 10 + qr) * SLW + 4 + qw * 4] = v;
        }
        __syncthreads();

        int cw = wid * 2;
        float u4[2][4];
#pragma unroll
        for (int cl = 0; cl < 2; cl++)
#pragma unroll
            for (int j = 0; j < 4; j++) u4[cl][j] = 0.f;

        for (int di = 0; di < 7; di++) {
            float a[7][4];
#pragma unroll
            for (int dj = 0; dj < 7; dj++) {
                uint2 p = *(const uint2*)&al[(di * 7 + dj) * 256 + r * 64 + wpx];
                a[dj][0] = __uint_as_float((p.x & 0xFFFFu) << 16);
                a[dj][1] = __uint_as_float(p.x & 0xFFFF0000u);
                a[dj][2] = __uint_as_float((p.y & 0xFFFFu) << 16);
                a[dj][3] = __uint_as_float(p.y & 0xFFFF0000u);
            }
#pragma unroll
            for (int cl = 0; cl < 2; cl++) {
                const float* rp = &st[((cw + cl) * 10 + r + di) * SLW + wpx];
                float rw[12];
                *(float4*)&rw[0] = *(const float4*)&rp[0];
                *(float4*)&rw[4] = *(const float4*)&rp[4];
                *(float4*)&rw[8] = *(const float4*)&rp[8];
#pragma unroll
                for (int dj = 0; dj < 7; dj++)
#pragma unroll
                    for (int j = 0; j < 4; j++)
                        u4[cl][j] = fmaf(a[dj][j], rw[j + dj + 1], u4[cl][j]);
            }
        }

#pragma unroll
        for (int cl = 0; cl < 2; cl++) {
            int c = c0 + cw + cl;
            float4 v = make_float4(u4[cl][0], u4[cl][1], u4[cl][2], u4[cl][3]);
            *(float4*)&ub[(size_t)c * PIX + (h0 + r) * 64 + wpx] = v;
        }
        __syncthreads();
    }
}

// ---------------------------------------------------------------------------
extern "C" void kernel_launch(void* const* d_in, const int* in_sizes, int n_in,
                              void* d_out, int out_size, void* d_ws, size_t ws_size,
                              hipStream_t stream) {
    const float* x  = (const float*)d_in[0];
    const float* w1 = (const float*)d_in[1];
    const float* w2 = (const float*)d_in[2];
    const float* w3 = (const float*)d_in[3];
    float* wsf = (float*)d_ws;

    prep<<<68, 256, 0, stream>>>(w1, w2, w3, wsf + M_OFF, wsf + WT3_OFF);
    convk<<<512, 256, 0, stream>>>(wsf + M_OFF, x, wsf + Z_OFF);               // z = M^T x
    simk2<<<896, 256, 0, stream>>>(wsf + Z_OFF, x, wsf + SIM_OFF);             // sim
    softpv2<<<512, 512, 0, stream>>>(wsf + SIM_OFF, x, wsf + U_OFF);           // attn, u
    convk<<<512, 256, 0, stream>>>(wsf + WT3_OFF, wsf + U_OFF, (float*)d_out); // out = W3 u
}